// Round 14
// baseline (182.719 us; speedup 1.0000x reference)
//
#include <hip/hip_runtime.h>

#define LQ 768
#define DIN 256
#define DB 128
#define NH 8
#define DH 32

// ws float offsets
#define OFF_QB 0
#define OFF_KT (LQ*DIN)          // kT[DIN][LQ]  transposed, pre-scaled K
#define OFF_VB (2*LQ*DIN)
#define OFF_GB (3*LQ*DIN)
#define OFF_W2 (4*LQ*DIN)
#define OFF_SC (OFF_W2 + DB*NH)
#define OFF_LG (OFF_SC + 16)     // logits[q][k][h] (bias-LN part only), 18.9 MB

// NT/streaming cache policy on the one-touch bias stream (aux=2):
// don't allocate in cache -> no L3/L2 thrash from the 302 MB stream.
__device__ __forceinline__ void gload_lds16_nt(const void* g, void* l) {
    __builtin_amdgcn_global_load_lds(
        (__attribute__((address_space(1))) const void*)g,
        (__attribute__((address_space(3))) void*)l,
        16, 0, 2);
}

// ---------------------------------------------------------------------------
// K1: proj (blocks 0..191, 4 rows each; K written transposed+scaled) +
//     setup (block 192: W2/S/C fold of the bias layernorm).
// ---------------------------------------------------------------------------
__global__ __launch_bounds__(256) void projsetup_kernel(
    const float* __restrict__ x, const float* __restrict__ lnw, const float* __restrict__ lnb,
    const float* __restrict__ Wq, const float* __restrict__ Wk, const float* __restrict__ Wv,
    const float* __restrict__ Wg, const float* __restrict__ bg,
    const float* __restrict__ lbw, const float* __restrict__ lbb, const float* __restrict__ Wb,
    float* __restrict__ qb, float* __restrict__ kT, float* __restrict__ vb, float* __restrict__ gb,
    float* __restrict__ W2, float* __restrict__ SC)
{
    const int tid = threadIdx.x;

    if (blockIdx.x == 192) {            // ---- setup ----
        if (tid < 128) {
            const int d = tid, lane = d & 63, wv = d >> 6;
            float w = lbw[d], b = lbb[d];
            float pS[NH], pC[NH];
            #pragma unroll
            for (int h = 0; h < NH; h++) {
                float wb = Wb[d*NH + h];
                float w2 = w * wb;
                W2[d*NH + h] = w2;
                pS[h] = w2;
                pC[h] = b * wb;
            }
            #pragma unroll
            for (int m = 1; m <= 32; m <<= 1) {
                #pragma unroll
                for (int h = 0; h < NH; h++) { pS[h] += __shfl_xor(pS[h], m); pC[h] += __shfl_xor(pC[h], m); }
            }
            __shared__ float red[2][16];
            if (lane == 0) {
                #pragma unroll
                for (int h = 0; h < NH; h++) { red[wv][h] = pS[h]; red[wv][NH+h] = pC[h]; }
            }
            __syncthreads();
            if (d < 16) SC[d] = red[0][d] + red[1][d];
        }
        return;
    }

    // ---- proj: 4 rows per block ----
    const int lane = tid & 63, rr = tid >> 6;
    const int row = blockIdx.x * 4 + rr;
    __shared__ float xn[4][DIN];

    float4 xv = ((const float4*)x)[row * (DIN/4) + lane];
    float s  = xv.x + xv.y + xv.z + xv.w;
    float ss = xv.x*xv.x + xv.y*xv.y + xv.z*xv.z + xv.w*xv.w;
    #pragma unroll
    for (int m = 1; m <= 32; m <<= 1) { s += __shfl_xor(s, m); ss += __shfl_xor(ss, m); }
    float mu  = s * (1.0f/DIN);
    float inv = rsqrtf(ss * (1.0f/DIN) - mu*mu + 1e-5f);
    float4 wv4 = ((const float4*)lnw)[lane];
    float4 bv4 = ((const float4*)lnb)[lane];
    float4 r4;
    r4.x = (xv.x - mu)*inv*wv4.x + bv4.x;
    r4.y = (xv.y - mu)*inv*wv4.y + bv4.y;
    r4.z = (xv.z - mu)*inv*wv4.z + bv4.z;
    r4.w = (xv.w - mu)*inv*wv4.w + bv4.w;
    *((float4*)&xn[rr][lane*4]) = r4;
    __syncthreads();

    const int col = tid;
    float aq[4] = {0,0,0,0}, ak[4] = {0,0,0,0}, av[4] = {0,0,0,0}, ag[4] = {0,0,0,0};
    for (int i4 = 0; i4 < DIN/4; i4++) {
        float4 x0 = *((const float4*)&xn[0][i4*4]);
        float4 x1 = *((const float4*)&xn[1][i4*4]);
        float4 x2 = *((const float4*)&xn[2][i4*4]);
        float4 x3 = *((const float4*)&xn[3][i4*4]);
        const float* p0 = (const float*)&x0;
        const float* p1 = (const float*)&x1;
        const float* p2 = (const float*)&x2;
        const float* p3 = (const float*)&x3;
        #pragma unroll
        for (int e = 0; e < 4; e++) {
            const int i = i4*4 + e;
            float wq = Wq[i*DIN + col], wk = Wk[i*DIN + col];
            float wvv = Wv[i*DIN + col], wg = Wg[i*DIN + col];
            aq[0] = fmaf(p0[e], wq, aq[0]); aq[1] = fmaf(p1[e], wq, aq[1]);
            aq[2] = fmaf(p2[e], wq, aq[2]); aq[3] = fmaf(p3[e], wq, aq[3]);
            ak[0] = fmaf(p0[e], wk, ak[0]); ak[1] = fmaf(p1[e], wk, ak[1]);
            ak[2] = fmaf(p2[e], wk, ak[2]); ak[3] = fmaf(p3[e], wk, ak[3]);
            av[0] = fmaf(p0[e], wvv, av[0]); av[1] = fmaf(p1[e], wvv, av[1]);
            av[2] = fmaf(p2[e], wvv, av[2]); av[3] = fmaf(p3[e], wvv, av[3]);
            ag[0] = fmaf(p0[e], wg, ag[0]); ag[1] = fmaf(p1[e], wg, ag[1]);
            ag[2] = fmaf(p2[e], wg, ag[2]); ag[3] = fmaf(p3[e], wg, ag[3]);
        }
    }
    const float kscale = 0.17677669529663687f;  // 1/sqrt(DH)
    float bgv = bg[col];
    #pragma unroll
    for (int r = 0; r < 4; r++) {
        const int orow = blockIdx.x*4 + r;
        qb[orow*DIN + col] = aq[r];
        vb[orow*DIN + col] = av[r];
        gb[orow*DIN + col] = 1.0f/(1.0f + __expf(-(ag[r] + bgv)));
    }
    *((float4*)&kT[col*LQ + blockIdx.x*4]) =
        make_float4(ak[0]*kscale, ak[1]*kscale, ak[2]*kscale, ak[3]*kscale);
}

// ---------------------------------------------------------------------------
// K2: bias streamer (R13-proven structure), NT cache policy on the stream.
// Grid (2, 768), block 128 (2 waves). LDS = 32KB -> 5 blocks/CU = 10 waves.
// Wave owns 192 keys = 3 key-blocks of 64; each key-block = 8 d-stages of
// 64 keys x 16 dims (4KB tile, 4x gload_lds). 4-buffer rotation, steady
// vmcnt(12), tail 8/4/0. Lane = key: private LN stats + 8-head projection.
// ---------------------------------------------------------------------------
__global__ __launch_bounds__(128) void bias13_kernel(
    const float* __restrict__ bias, const float* __restrict__ W2g,
    const float* __restrict__ SCg, float* __restrict__ logits)
{
    __shared__ float tiles[2][4][1024];   // [wave][buf][4KB] = 32KB
    const int tid  = threadIdx.x;
    const int w    = tid >> 6;
    const int lane = tid & 63;            // = key within 64-key block
    const int q    = blockIdx.y;
    const int keybase = blockIdx.x * 384 + w * 192;

    const char* gq = (const char*)bias + ((size_t)q*LQ + keybase) * (DB*4);
    char* const lb0 = (char*)&tiles[w][0][0];

    // staging source offset (R12 involution): lane l' writes LDS
    // A = c*1024+l'*16; content dim-group rot = ((l'&3)-((l'>>3)&3))&3.
    const int keyc = lane >> 2;
    const int rot  = ((lane & 3) - ((lane >> 3) & 3)) & 3;
    const int soff = keyc*512 + rot*16;

    #define STAGE(T) {                                                       \
        const char* gt = gq + ((T) >> 3)*32768 + ((T) & 7)*64;               \
        char* lb = lb0 + (((T) & 3) << 12);                                  \
        _Pragma("unroll")                                                    \
        for (int c = 0; c < 4; c++)                                          \
            gload_lds16_nt(gt + c*8192 + soff, lb + c*1024);                 \
    }

    // prologue: 4 tiles in flight
    STAGE(0); STAGE(1); STAGE(2); STAGE(3);

    float Sh[NH], Ch[NH];
    #pragma unroll
    for (int h = 0; h < NH; h++) { Sh[h] = SCg[h]; Ch[h] = SCg[NH + h]; }

    const int a0 = lane * 64;
    const int rl = (lane >> 1) & 3;

    float lo[3][NH];

    #pragma unroll
    for (int kb = 0; kb < 3; kb++) {
        float s = 0.f, ss = 0.f;
        float acc[NH] = {0,0,0,0,0,0,0,0};
        #pragma unroll 1
        for (int sd = 0; sd < 8; sd++) {
            const int T = kb*8 + sd;
            if (T <= 20)      asm volatile("s_waitcnt vmcnt(12)" ::: "memory");
            else if (T == 21) asm volatile("s_waitcnt vmcnt(8)"  ::: "memory");
            else if (T == 22) asm volatile("s_waitcnt vmcnt(4)"  ::: "memory");
            else              asm volatile("s_waitcnt vmcnt(0)"  ::: "memory");

            const char* tb = lb0 + ((T & 3) << 12);
            const float* wr0 = W2g + sd*16*NH;            // wave-uniform
            #pragma unroll
            for (int j = 0; j < 4; j++) {
                float4 bv = *(const float4*)(tb + a0 + (((rl + j) & 3) << 4));
                const float* wr = wr0 + j*4*NH;
                #pragma unroll
                for (int e = 0; e < 4; e++) {
                    float xv = (&bv.x)[e];
                    s += xv; ss = fmaf(xv, xv, ss);
                    #pragma unroll
                    for (int h = 0; h < NH; h++)
                        acc[h] = fmaf(xv, wr[e*NH + h], acc[h]);
                }
            }
            asm volatile("s_waitcnt lgkmcnt(0)" ::: "memory");  // WAR: reads done
            if (T + 4 < 24) STAGE(T + 4);
        }
        float mu  = s * (1.0f/DB);
        float inv = rsqrtf(ss * (1.0f/DB) - mu*mu + 1e-5f);
        #pragma unroll
        for (int h = 0; h < NH; h++)
            lo[kb][h] = fmaf(inv, fmaf(-mu, Sh[h], acc[h]), Ch[h]);
    }
    #undef STAGE

    // all DMA retired (vmcnt(0) above) -> store logits, coalesced
    #pragma unroll
    for (int kb = 0; kb < 3; kb++) {
        float4* dst = (float4*)(logits + ((size_t)q*LQ + keybase + kb*64 + lane)*NH);
        dst[0] = make_float4(lo[kb][0], lo[kb][1], lo[kb][2], lo[kb][3]);
        dst[1] = make_float4(lo[kb][4], lo[kb][5], lo[kb][6], lo[kb][7]);
    }
}

// ---------------------------------------------------------------------------
// K3: attn tail (R5-proven): logits -> pT transposed, add qk from kT,
// softmax (contiguous float4 rows), PV, gate, Wo. 2 q-rows/block, grid 384.
// ---------------------------------------------------------------------------
__global__ __launch_bounds__(256) void attn_kernel(
    const float* __restrict__ logits, const float* __restrict__ qbuf,
    const float* __restrict__ kT, const float* __restrict__ vbuf,
    const float* __restrict__ gb, const float* __restrict__ Wo,
    const float* __restrict__ bo, float* __restrict__ out)
{
    const int tid = threadIdx.x;
    const int q0 = blockIdx.x * 2;
    __shared__ float pT[2][NH][776];
    __shared__ float ao[2][DIN];
    __shared__ float isum[2][NH];

    #pragma unroll
    for (int r = 0; r < 2; r++) {
        const float4* rp = (const float4*)(logits + (size_t)(q0 + r)*LQ*NH);
        #pragma unroll
        for (int ii = 0; ii < 6; ii++) {
            int jj = ii*256 + tid;
            float4 t = rp[jj];
            int k = jj >> 1, h0 = (jj & 1) << 2;
            pT[r][h0+0][k] = t.x; pT[r][h0+1][k] = t.y;
            pT[r][h0+2][k] = t.z; pT[r][h0+3][k] = t.w;
        }
    }
    __syncthreads();

    if (tid < 192) {
        const float* q0p = qbuf + (size_t)q0*DIN;
        const float* q1p = q0p + DIN;
        #pragma unroll
        for (int h = 0; h < NH; h++) {
            float a00=0,a01=0,a02=0,a03=0, a10=0,a11=0,a12=0,a13=0;
            #pragma unroll
            for (int dd = 0; dd < DH; dd++) {
                const int d = h*DH + dd;
                float4 kv = *(const float4*)(kT + (size_t)d*LQ + tid*4);
                float qa = q0p[d], qc = q1p[d];
                a00 = fmaf(qa, kv.x, a00); a01 = fmaf(qa, kv.y, a01);
                a02 = fmaf(qa, kv.z, a02); a03 = fmaf(qa, kv.w, a03);
                a10 = fmaf(qc, kv.x, a10); a11 = fmaf(qc, kv.y, a11);
                a12 = fmaf(qc, kv.z, a12); a13 = fmaf(qc, kv.w, a13);
            }
            float4 p0 = *(float4*)&pT[0][h][tid*4];
            p0.x += a00; p0.y += a01; p0.z += a02; p0.w += a03;
            *(float4*)&pT[0][h][tid*4] = p0;
            float4 p1 = *(float4*)&pT[1][h][tid*4];
            p1.x += a10; p1.y += a11; p1.z += a12; p1.w += a13;
            *(float4*)&pT[1][h][tid*4] = p1;
        }
    }
    __syncthreads();

    {
        const int r = tid >> 7, h = (tid >> 4) & 7, l = tid & 15;
        float4* row = (float4*)&pT[r][h][0];
        float m = -1e30f;
        for (int i = l; i < 192; i += 16) {
            float4 v = row[i];
            m = fmaxf(m, fmaxf(fmaxf(v.x, v.y), fmaxf(v.z, v.w)));
        }
        #pragma unroll
        for (int mm = 1; mm <= 8; mm <<= 1) m = fmaxf(m, __shfl_xor(m, mm));
        float sum = 0.f;
        for (int i = l; i < 192; i += 16) {
            float4 v = row[i];
            v.x = __expf(v.x - m); v.y = __expf(v.y - m);
            v.z = __expf(v.z - m); v.w = __expf(v.w - m);
            sum += v.x + v.y + v.z + v.w;
            row[i] = v;
        }
        #pragma unroll
        for (int mm = 1; mm <= 8; mm <<= 1) sum += __shfl_xor(sum, mm);
        if (l == 0) isum[r][h] = 1.0f / sum;
    }
    __syncthreads();

    {
        const int h = tid >> 5, d = tid & 31;
        const float* vp = vbuf + h*DH + d;
        const float4* p0r = (const float4*)&pT[0][h][0];
        const float4* p1r = (const float4*)&pT[1][h][0];
        float a0 = 0.f, a1 = 0.f;
        for (int k4 = 0; k4 < 192; k4++) {
            float4 p0 = p0r[k4], p1 = p1r[k4];
            float v0 = vp[(size_t)(k4*4+0)*DIN];
            float v1 = vp[(size_t)(k4*4+1)*DIN];
            float v2 = vp[(size_t)(k4*4+2)*DIN];
            float v3 = vp[(size_t)(k4*4+3)*DIN];
            a0 = fmaf(p0.x, v0, a0); a0 = fmaf(p0.y, v1, a0);
            a0 = fmaf(p0.z, v2, a0); a0 = fmaf(p0.w, v3, a0);
            a1 = fmaf(p1.x, v0, a1); a1 = fmaf(p1.y, v1, a1);
            a1 = fmaf(p1.z, v2, a1); a1 = fmaf(p1.w, v3, a1);
        }
        ao[0][tid] = a0 * isum[0][h] * gb[(q0+0)*DIN + tid];
        ao[1][tid] = a1 * isum[1][h] * gb[(q0+1)*DIN + tid];
    }
    __syncthreads();

    {
        const int col = tid;
        float o0 = bo[col], o1 = o0;
        for (int i = 0; i < DIN; i++) {
            float wv = Wo[i*DIN + col];
            o0 = fmaf(ao[0][i], wv, o0);
            o1 = fmaf(ao[1][i], wv, o1);
        }
        out[(q0+0)*DIN + col] = o0;
        out[(q0+1)*DIN + col] = o1;
    }
}

extern "C" void kernel_launch(void* const* d_in, const int* in_sizes, int n_in,
                              void* d_out, int out_size, void* d_ws, size_t ws_size,
                              hipStream_t stream) {
    const float* x    = (const float*)d_in[0];
    const float* bias = (const float*)d_in[1];
    const float* lnw  = (const float*)d_in[2];
    const float* lnb  = (const float*)d_in[3];
    const float* lbw  = (const float*)d_in[4];
    const float* lbb  = (const float*)d_in[5];
    const float* Wq   = (const float*)d_in[6];
    const float* Wk   = (const float*)d_in[7];
    const float* Wv   = (const float*)d_in[8];
    const float* Wb   = (const float*)d_in[9];
    const float* Wg   = (const float*)d_in[10];
    const float* bg   = (const float*)d_in[11];
    const float* Wo   = (const float*)d_in[12];
    const float* bo   = (const float*)d_in[13];

    float* ws = (float*)d_ws;
    float* qb = ws + OFF_QB;
    float* kT = ws + OFF_KT;
    float* vb = ws + OFF_VB;
    float* gb = ws + OFF_GB;
    float* W2 = ws + OFF_W2;
    float* SC = ws + OFF_SC;
    float* lg = ws + OFF_LG;

    projsetup_kernel<<<193, 256, 0, stream>>>(x, lnw, lnb, Wq, Wk, Wv, Wg, bg,
                                              lbw, lbb, Wb, qb, kT, vb, gb, W2, SC);
    bias13_kernel<<<dim3(2, LQ), 128, 0, stream>>>(bias, W2, SC, lg);
    attn_kernel<<<LQ/2, 256, 0, stream>>>(lg, qb, kT, vb, gb, Wo, bo, (float*)d_out);
}

// Round 15
// 170.121 us; speedup vs baseline: 1.0741x; 1.0741x over previous
//
#include <hip/hip_runtime.h>

#define LQ 768
#define DIN 256
#define DB 128
#define NH 8
#define DH 32

// ws float offsets
#define OFF_QB 0
#define OFF_KT (LQ*DIN)          // kT[DIN][LQ]  transposed, pre-scaled K
#define OFF_VB (2*LQ*DIN)
#define OFF_GB (3*LQ*DIN)
#define OFF_W2 (4*LQ*DIN)
#define OFF_SC (OFF_W2 + DB*NH)
#define OFF_LG (OFF_SC + 16)     // logits[q][k][h] (bias-LN part only), 18.9 MB

__device__ __forceinline__ void gload_lds16(const void* g, void* l) {
    __builtin_amdgcn_global_load_lds(
        (__attribute__((address_space(1))) const void*)g,
        (__attribute__((address_space(3))) void*)l,
        16, 0, 0);
}

// ---------------------------------------------------------------------------
// K1: proj (blocks 0..191, 4 rows each; K written transposed+scaled) +
//     setup (block 192: W2/S/C fold of the bias layernorm).
// ---------------------------------------------------------------------------
__global__ __launch_bounds__(256) void projsetup_kernel(
    const float* __restrict__ x, const float* __restrict__ lnw, const float* __restrict__ lnb,
    const float* __restrict__ Wq, const float* __restrict__ Wk, const float* __restrict__ Wv,
    const float* __restrict__ Wg, const float* __restrict__ bg,
    const float* __restrict__ lbw, const float* __restrict__ lbb, const float* __restrict__ Wb,
    float* __restrict__ qb, float* __restrict__ kT, float* __restrict__ vb, float* __restrict__ gb,
    float* __restrict__ W2, float* __restrict__ SC)
{
    const int tid = threadIdx.x;

    if (blockIdx.x == 192) {            // ---- setup ----
        if (tid < 128) {
            const int d = tid, lane = d & 63, wv = d >> 6;
            float w = lbw[d], b = lbb[d];
            float pS[NH], pC[NH];
            #pragma unroll
            for (int h = 0; h < NH; h++) {
                float wb = Wb[d*NH + h];
                float w2 = w * wb;
                W2[d*NH + h] = w2;
                pS[h] = w2;
                pC[h] = b * wb;
            }
            #pragma unroll
            for (int m = 1; m <= 32; m <<= 1) {
                #pragma unroll
                for (int h = 0; h < NH; h++) { pS[h] += __shfl_xor(pS[h], m); pC[h] += __shfl_xor(pC[h], m); }
            }
            __shared__ float red[2][16];
            if (lane == 0) {
                #pragma unroll
                for (int h = 0; h < NH; h++) { red[wv][h] = pS[h]; red[wv][NH+h] = pC[h]; }
            }
            __syncthreads();
            if (d < 16) SC[d] = red[0][d] + red[1][d];
        }
        return;
    }

    // ---- proj: 4 rows per block ----
    const int lane = tid & 63, rr = tid >> 6;
    const int row = blockIdx.x * 4 + rr;
    __shared__ float xn[4][DIN];

    float4 xv = ((const float4*)x)[row * (DIN/4) + lane];
    float s  = xv.x + xv.y + xv.z + xv.w;
    float ss = xv.x*xv.x + xv.y*xv.y + xv.z*xv.z + xv.w*xv.w;
    #pragma unroll
    for (int m = 1; m <= 32; m <<= 1) { s += __shfl_xor(s, m); ss += __shfl_xor(ss, m); }
    float mu  = s * (1.0f/DIN);
    float inv = rsqrtf(ss * (1.0f/DIN) - mu*mu + 1e-5f);
    float4 wv4 = ((const float4*)lnw)[lane];
    float4 bv4 = ((const float4*)lnb)[lane];
    float4 r4;
    r4.x = (xv.x - mu)*inv*wv4.x + bv4.x;
    r4.y = (xv.y - mu)*inv*wv4.y + bv4.y;
    r4.z = (xv.z - mu)*inv*wv4.z + bv4.z;
    r4.w = (xv.w - mu)*inv*wv4.w + bv4.w;
    *((float4*)&xn[rr][lane*4]) = r4;
    __syncthreads();

    const int col = tid;
    float aq[4] = {0,0,0,0}, ak[4] = {0,0,0,0}, av[4] = {0,0,0,0}, ag[4] = {0,0,0,0};
    for (int i4 = 0; i4 < DIN/4; i4++) {
        float4 x0 = *((const float4*)&xn[0][i4*4]);
        float4 x1 = *((const float4*)&xn[1][i4*4]);
        float4 x2 = *((const float4*)&xn[2][i4*4]);
        float4 x3 = *((const float4*)&xn[3][i4*4]);
        const float* p0 = (const float*)&x0;
        const float* p1 = (const float*)&x1;
        const float* p2 = (const float*)&x2;
        const float* p3 = (const float*)&x3;
        #pragma unroll
        for (int e = 0; e < 4; e++) {
            const int i = i4*4 + e;
            float wq = Wq[i*DIN + col], wk = Wk[i*DIN + col];
            float wvv = Wv[i*DIN + col], wg = Wg[i*DIN + col];
            aq[0] = fmaf(p0[e], wq, aq[0]); aq[1] = fmaf(p1[e], wq, aq[1]);
            aq[2] = fmaf(p2[e], wq, aq[2]); aq[3] = fmaf(p3[e], wq, aq[3]);
            ak[0] = fmaf(p0[e], wk, ak[0]); ak[1] = fmaf(p1[e], wk, ak[1]);
            ak[2] = fmaf(p2[e], wk, ak[2]); ak[3] = fmaf(p3[e], wk, ak[3]);
            av[0] = fmaf(p0[e], wvv, av[0]); av[1] = fmaf(p1[e], wvv, av[1]);
            av[2] = fmaf(p2[e], wvv, av[2]); av[3] = fmaf(p3[e], wvv, av[3]);
            ag[0] = fmaf(p0[e], wg, ag[0]); ag[1] = fmaf(p1[e], wg, ag[1]);
            ag[2] = fmaf(p2[e], wg, ag[2]); ag[3] = fmaf(p3[e], wg, ag[3]);
        }
    }
    const float kscale = 0.17677669529663687f;  // 1/sqrt(DH)
    float bgv = bg[col];
    #pragma unroll
    for (int r = 0; r < 4; r++) {
        const int orow = blockIdx.x*4 + r;
        qb[orow*DIN + col] = aq[r];
        vb[orow*DIN + col] = av[r];
        gb[orow*DIN + col] = 1.0f/(1.0f + __expf(-(ag[r] + bgv)));
    }
    *((float4*)&kT[col*LQ + blockIdx.x*4]) =
        make_float4(ak[0]*kscale, ak[1]*kscale, ak[2]*kscale, ak[3]*kscale);
}

// ---------------------------------------------------------------------------
// K2: bias streamer (R13-proven, aux=0 reverted). Grid (2, 768), block 128
// (2 waves). LDS 32KB -> 5 blocks/CU = 10 waves. Wave owns 192 keys =
// 3 key-blocks of 64; each = 8 d-stages of 64 keys x 16 dims (4KB tile,
// 4x gload_lds). 4-buffer rotation, steady vmcnt(12), tail 8/4/0.
// Lane = key: private LN stats + 8-head projection (no shuffles, no W2-LDS).
// ---------------------------------------------------------------------------
__global__ __launch_bounds__(128) void bias13_kernel(
    const float* __restrict__ bias, const float* __restrict__ W2g,
    const float* __restrict__ SCg, float* __restrict__ logits)
{
    __shared__ float tiles[2][4][1024];   // [wave][buf][4KB] = 32KB
    const int tid  = threadIdx.x;
    const int w    = tid >> 6;
    const int lane = tid & 63;            // = key within 64-key block
    const int q    = blockIdx.y;
    const int keybase = blockIdx.x * 384 + w * 192;

    const char* gq = (const char*)bias + ((size_t)q*LQ + keybase) * (DB*4);
    char* const lb0 = (char*)&tiles[w][0][0];

    // staging source offset (R12 involution): lane l' writes LDS
    // A = c*1024+l'*16; content dim-group rot = ((l'&3)-((l'>>3)&3))&3.
    const int keyc = lane >> 2;
    const int rot  = ((lane & 3) - ((lane >> 3) & 3)) & 3;
    const int soff = keyc*512 + rot*16;

    #define STAGE(T) {                                                       \
        const char* gt = gq + ((T) >> 3)*32768 + ((T) & 7)*64;               \
        char* lb = lb0 + (((T) & 3) << 12);                                  \
        _Pragma("unroll")                                                    \
        for (int c = 0; c < 4; c++)                                          \
            gload_lds16(gt + c*8192 + soff, lb + c*1024);                    \
    }

    // prologue: 4 tiles in flight
    STAGE(0); STAGE(1); STAGE(2); STAGE(3);

    float Sh[NH], Ch[NH];
    #pragma unroll
    for (int h = 0; h < NH; h++) { Sh[h] = SCg[h]; Ch[h] = SCg[NH + h]; }

    const int a0 = lane * 64;
    const int rl = (lane >> 1) & 3;

    float lo[3][NH];

    #pragma unroll
    for (int kb = 0; kb < 3; kb++) {
        float s = 0.f, ss = 0.f;
        float acc[NH] = {0,0,0,0,0,0,0,0};
        #pragma unroll 1
        for (int sd = 0; sd < 8; sd++) {
            const int T = kb*8 + sd;
            if (T <= 20)      asm volatile("s_waitcnt vmcnt(12)" ::: "memory");
            else if (T == 21) asm volatile("s_waitcnt vmcnt(8)"  ::: "memory");
            else if (T == 22) asm volatile("s_waitcnt vmcnt(4)"  ::: "memory");
            else              asm volatile("s_waitcnt vmcnt(0)"  ::: "memory");

            const char* tb = lb0 + ((T & 3) << 12);
            const float* wr0 = W2g + sd*16*NH;            // wave-uniform
            #pragma unroll
            for (int j = 0; j < 4; j++) {
                float4 bv = *(const float4*)(tb + a0 + (((rl + j) & 3) << 4));
                const float* wr = wr0 + j*4*NH;
                #pragma unroll
                for (int e = 0; e < 4; e++) {
                    float xv = (&bv.x)[e];
                    s += xv; ss = fmaf(xv, xv, ss);
                    #pragma unroll
                    for (int h = 0; h < NH; h++)
                        acc[h] = fmaf(xv, wr[e*NH + h], acc[h]);
                }
            }
            asm volatile("s_waitcnt lgkmcnt(0)" ::: "memory");  // WAR: reads done
            if (T + 4 < 24) STAGE(T + 4);
        }
        float mu  = s * (1.0f/DB);
        float inv = rsqrtf(ss * (1.0f/DB) - mu*mu + 1e-5f);
        #pragma unroll
        for (int h = 0; h < NH; h++)
            lo[kb][h] = fmaf(inv, fmaf(-mu, Sh[h], acc[h]), Ch[h]);
    }
    #undef STAGE

    // all DMA retired (vmcnt(0) above) -> store logits, coalesced
    #pragma unroll
    for (int kb = 0; kb < 3; kb++) {
        float4* dst = (float4*)(logits + ((size_t)q*LQ + keybase + kb*64 + lane)*NH);
        dst[0] = make_float4(lo[kb][0], lo[kb][1], lo[kb][2], lo[kb][3]);
        dst[1] = make_float4(lo[kb][4], lo[kb][5], lo[kb][6], lo[kb][7]);
    }
}

// ---------------------------------------------------------------------------
// K3: attn tail, 4 q-rows per block (halves kT/V/Wo L2 traffic vs 2-row).
// Grid 192, 256 threads, pT[4][8][776] = 99KB LDS -> 1 block/CU.
// kT fragments read once per block, serve 4 rows from registers.
// ---------------------------------------------------------------------------
__global__ __launch_bounds__(256) void attn_kernel(
    const float* __restrict__ logits, const float* __restrict__ qbuf,
    const float* __restrict__ kT, const float* __restrict__ vbuf,
    const float* __restrict__ gb, const float* __restrict__ Wo,
    const float* __restrict__ bo, float* __restrict__ out)
{
    const int tid = threadIdx.x;
    const int q0 = blockIdx.x * 4;
    __shared__ float pT[4][NH][776];
    __shared__ float ao[4][DIN];
    __shared__ float isum[4][NH];

    #pragma unroll
    for (int r = 0; r < 4; r++) {
        const float4* rp = (const float4*)(logits + (size_t)(q0 + r)*LQ*NH);
        #pragma unroll
        for (int ii = 0; ii < 6; ii++) {
            int jj = ii*256 + tid;
            float4 t = rp[jj];
            int k = jj >> 1, h0 = (jj & 1) << 2;
            pT[r][h0+0][k] = t.x; pT[r][h0+1][k] = t.y;
            pT[r][h0+2][k] = t.z; pT[r][h0+3][k] = t.w;
        }
    }
    __syncthreads();

    // qk: threads 0..191, 4 keys each; kT fragment loaded once, serves 4 rows.
    if (tid < 192) {
        const float* qp = qbuf + (size_t)q0*DIN;          // uniform -> s_load
        #pragma unroll
        for (int h = 0; h < NH; h++) {
            float a[4][4];
            #pragma unroll
            for (int r = 0; r < 4; r++)
                #pragma unroll
                for (int e = 0; e < 4; e++) a[r][e] = 0.f;
            #pragma unroll
            for (int dd = 0; dd < DH; dd++) {
                const int d = h*DH + dd;
                float4 kv = *(const float4*)(kT + (size_t)d*LQ + tid*4);
                #pragma unroll
                for (int r = 0; r < 4; r++) {
                    float qa = qp[r*DIN + d];
                    a[r][0] = fmaf(qa, kv.x, a[r][0]);
                    a[r][1] = fmaf(qa, kv.y, a[r][1]);
                    a[r][2] = fmaf(qa, kv.z, a[r][2]);
                    a[r][3] = fmaf(qa, kv.w, a[r][3]);
                }
            }
            #pragma unroll
            for (int r = 0; r < 4; r++) {
                float4 p = *(float4*)&pT[r][h][tid*4];
                p.x += a[r][0]; p.y += a[r][1]; p.z += a[r][2]; p.w += a[r][3];
                *(float4*)&pT[r][h][tid*4] = p;
            }
        }
    }
    __syncthreads();

    // softmax: 32 (r,h) pairs x 8 lanes
    {
        const int pair = tid >> 3, l = tid & 7;
        const int r = pair >> 3, h = pair & 7;
        float4* row = (float4*)&pT[r][h][0];
        float m = -1e30f;
        for (int i = l; i < 192; i += 8) {
            float4 v = row[i];
            m = fmaxf(m, fmaxf(fmaxf(v.x, v.y), fmaxf(v.z, v.w)));
        }
        #pragma unroll
        for (int mm = 1; mm <= 4; mm <<= 1) m = fmaxf(m, __shfl_xor(m, mm));
        float sum = 0.f;
        for (int i = l; i < 192; i += 8) {
            float4 v = row[i];
            v.x = __expf(v.x - m); v.y = __expf(v.y - m);
            v.z = __expf(v.z - m); v.w = __expf(v.w - m);
            sum += v.x + v.y + v.z + v.w;
            row[i] = v;
        }
        #pragma unroll
        for (int mm = 1; mm <= 4; mm <<= 1) sum += __shfl_xor(sum, mm);
        if (l == 0) isum[r][h] = 1.0f / sum;
    }
    __syncthreads();

    // PV + gate: thread (h, d) handles all 4 rows; V reads shared.
    {
        const int h = tid >> 5, d = tid & 31;
        const float* vp = vbuf + h*DH + d;
        const float4* pr0 = (const float4*)&pT[0][h][0];
        const float4* pr1 = (const float4*)&pT[1][h][0];
        const float4* pr2 = (const float4*)&pT[2][h][0];
        const float4* pr3 = (const float4*)&pT[3][h][0];
        float a0 = 0.f, a1 = 0.f, a2 = 0.f, a3 = 0.f;
        for (int k4 = 0; k4 < 192; k4++) {
            float v0 = vp[(size_t)(k4*4+0)*DIN];
            float v1 = vp[(size_t)(k4*4+1)*DIN];
            float v2 = vp[(size_t)(k4*4+2)*DIN];
            float v3 = vp[(size_t)(k4*4+3)*DIN];
            float4 p0 = pr0[k4], p1 = pr1[k4], p2 = pr2[k4], p3 = pr3[k4];
            a0 = fmaf(p0.x, v0, a0); a0 = fmaf(p0.y, v1, a0);
            a0 = fmaf(p0.z, v2, a0); a0 = fmaf(p0.w, v3, a0);
            a1 = fmaf(p1.x, v0, a1); a1 = fmaf(p1.y, v1, a1);
            a1 = fmaf(p1.z, v2, a1); a1 = fmaf(p1.w, v3, a1);
            a2 = fmaf(p2.x, v0, a2); a2 = fmaf(p2.y, v1, a2);
            a2 = fmaf(p2.z, v2, a2); a2 = fmaf(p2.w, v3, a2);
            a3 = fmaf(p3.x, v0, a3); a3 = fmaf(p3.y, v1, a3);
            a3 = fmaf(p3.z, v2, a3); a3 = fmaf(p3.w, v3, a3);
        }
        ao[0][tid] = a0 * isum[0][h] * gb[(size_t)(q0+0)*DIN + tid];
        ao[1][tid] = a1 * isum[1][h] * gb[(size_t)(q0+1)*DIN + tid];
        ao[2][tid] = a2 * isum[2][h] * gb[(size_t)(q0+2)*DIN + tid];
        ao[3][tid] = a3 * isum[3][h] * gb[(size_t)(q0+3)*DIN + tid];
    }
    __syncthreads();

    // output projection: Wo read once per block, serves 4 rows.
    {
        const int col = tid;
        float bov = bo[col];
        float o0 = bov, o1 = bov, o2 = bov, o3 = bov;
        for (int i = 0; i < DIN; i++) {
            float wv = Wo[i*DIN + col];
            o0 = fmaf(ao[0][i], wv, o0);
            o1 = fmaf(ao[1][i], wv, o1);
            o2 = fmaf(ao[2][i], wv, o2);
            o3 = fmaf(ao[3][i], wv, o3);
        }
        out[(size_t)(q0+0)*DIN + col] = o0;
        out[(size_t)(q0+1)*DIN + col] = o1;
        out[(size_t)(q0+2)*DIN + col] = o2;
        out[(size_t)(q0+3)*DIN + col] = o3;
    }
}

extern "C" void kernel_launch(void* const* d_in, const int* in_sizes, int n_in,
                              void* d_out, int out_size, void* d_ws, size_t ws_size,
                              hipStream_t stream) {
    const float* x    = (const float*)d_in[0];
    const float* bias = (const float*)d_in[1];
    const float* lnw  = (const float*)d_in[2];
    const float* lnb  = (const float*)d_in[3];
    const float* lbw  = (const float*)d_in[4];
    const float* lbb  = (const float*)d_in[5];
    const float* Wq   = (const float*)d_in[6];
    const float* Wk   = (const float*)d_in[7];
    const float* Wv   = (const float*)d_in[8];
    const float* Wb   = (const float*)d_in[9];
    const float* Wg   = (const float*)d_in[10];
    const float* bg   = (const float*)d_in[11];
    const float* Wo   = (const float*)d_in[12];
    const float* bo   = (const float*)d_in[13];

    float* ws = (float*)d_ws;
    float* qb = ws + OFF_QB;
    float* kT = ws + OFF_KT;
    float* vb = ws + OFF_VB;
    float* gb = ws + OFF_GB;
    float* W2 = ws + OFF_W2;
    float* SC = ws + OFF_SC;
    float* lg = ws + OFF_LG;

    projsetup_kernel<<<193, 256, 0, stream>>>(x, lnw, lnb, Wq, Wk, Wv, Wg, bg,
                                              lbw, lbb, Wb, qb, kT, vb, gb, W2, SC);
    bias13_kernel<<<dim3(2, LQ), 128, 0, stream>>>(bias, W2, SC, lg);
    attn_kernel<<<LQ/4, 256, 0, stream>>>(lg, qb, kT, vb, gb, Wo, bo, (float*)d_out);
}

// Round 16
// 154.964 us; speedup vs baseline: 1.1791x; 1.0978x over previous
//
#include <hip/hip_runtime.h>

#define LQ 768
#define DIN 256
#define DB 128
#define NH 8
#define DH 32

// ws float offsets
#define OFF_QB 0
#define OFF_KT (LQ*DIN)          // kT[DIN][LQ]  transposed, pre-scaled K
#define OFF_VB (2*LQ*DIN)
#define OFF_GB (3*LQ*DIN)
#define OFF_W2 (4*LQ*DIN)
#define OFF_SC (OFF_W2 + DB*NH)
#define OFF_LG (OFF_SC + 16)     // logits[q][k][h] (bias-LN part only), 18.9 MB

__device__ __forceinline__ void gload_lds16(const void* g, void* l) {
    __builtin_amdgcn_global_load_lds(
        (__attribute__((address_space(1))) const void*)g,
        (__attribute__((address_space(3))) void*)l,
        16, 0, 0);
}

// ---------------------------------------------------------------------------
// K1: proj (blocks 0..191, 4 rows each; K written transposed+scaled) +
//     setup (block 192: W2/S/C fold of the bias layernorm).
// ---------------------------------------------------------------------------
__global__ __launch_bounds__(256) void projsetup_kernel(
    const float* __restrict__ x, const float* __restrict__ lnw, const float* __restrict__ lnb,
    const float* __restrict__ Wq, const float* __restrict__ Wk, const float* __restrict__ Wv,
    const float* __restrict__ Wg, const float* __restrict__ bg,
    const float* __restrict__ lbw, const float* __restrict__ lbb, const float* __restrict__ Wb,
    float* __restrict__ qb, float* __restrict__ kT, float* __restrict__ vb, float* __restrict__ gb,
    float* __restrict__ W2, float* __restrict__ SC)
{
    const int tid = threadIdx.x;

    if (blockIdx.x == 192) {            // ---- setup ----
        if (tid < 128) {
            const int d = tid, lane = d & 63, wv = d >> 6;
            float w = lbw[d], b = lbb[d];
            float pS[NH], pC[NH];
            #pragma unroll
            for (int h = 0; h < NH; h++) {
                float wb = Wb[d*NH + h];
                float w2 = w * wb;
                W2[d*NH + h] = w2;
                pS[h] = w2;
                pC[h] = b * wb;
            }
            #pragma unroll
            for (int m = 1; m <= 32; m <<= 1) {
                #pragma unroll
                for (int h = 0; h < NH; h++) { pS[h] += __shfl_xor(pS[h], m); pC[h] += __shfl_xor(pC[h], m); }
            }
            __shared__ float red[2][16];
            if (lane == 0) {
                #pragma unroll
                for (int h = 0; h < NH; h++) { red[wv][h] = pS[h]; red[wv][NH+h] = pC[h]; }
            }
            __syncthreads();
            if (d < 16) SC[d] = red[0][d] + red[1][d];
        }
        return;
    }

    // ---- proj: 4 rows per block ----
    const int lane = tid & 63, rr = tid >> 6;
    const int row = blockIdx.x * 4 + rr;
    __shared__ float xn[4][DIN];

    float4 xv = ((const float4*)x)[row * (DIN/4) + lane];
    float s  = xv.x + xv.y + xv.z + xv.w;
    float ss = xv.x*xv.x + xv.y*xv.y + xv.z*xv.z + xv.w*xv.w;
    #pragma unroll
    for (int m = 1; m <= 32; m <<= 1) { s += __shfl_xor(s, m); ss += __shfl_xor(ss, m); }
    float mu  = s * (1.0f/DIN);
    float inv = rsqrtf(ss * (1.0f/DIN) - mu*mu + 1e-5f);
    float4 wv4 = ((const float4*)lnw)[lane];
    float4 bv4 = ((const float4*)lnb)[lane];
    float4 r4;
    r4.x = (xv.x - mu)*inv*wv4.x + bv4.x;
    r4.y = (xv.y - mu)*inv*wv4.y + bv4.y;
    r4.z = (xv.z - mu)*inv*wv4.z + bv4.z;
    r4.w = (xv.w - mu)*inv*wv4.w + bv4.w;
    *((float4*)&xn[rr][lane*4]) = r4;
    __syncthreads();

    const int col = tid;
    float aq[4] = {0,0,0,0}, ak[4] = {0,0,0,0}, av[4] = {0,0,0,0}, ag[4] = {0,0,0,0};
    for (int i4 = 0; i4 < DIN/4; i4++) {
        float4 x0 = *((const float4*)&xn[0][i4*4]);
        float4 x1 = *((const float4*)&xn[1][i4*4]);
        float4 x2 = *((const float4*)&xn[2][i4*4]);
        float4 x3 = *((const float4*)&xn[3][i4*4]);
        const float* p0 = (const float*)&x0;
        const float* p1 = (const float*)&x1;
        const float* p2 = (const float*)&x2;
        const float* p3 = (const float*)&x3;
        #pragma unroll
        for (int e = 0; e < 4; e++) {
            const int i = i4*4 + e;
            float wq = Wq[i*DIN + col], wk = Wk[i*DIN + col];
            float wvv = Wv[i*DIN + col], wg = Wg[i*DIN + col];
            aq[0] = fmaf(p0[e], wq, aq[0]); aq[1] = fmaf(p1[e], wq, aq[1]);
            aq[2] = fmaf(p2[e], wq, aq[2]); aq[3] = fmaf(p3[e], wq, aq[3]);
            ak[0] = fmaf(p0[e], wk, ak[0]); ak[1] = fmaf(p1[e], wk, ak[1]);
            ak[2] = fmaf(p2[e], wk, ak[2]); ak[3] = fmaf(p3[e], wk, ak[3]);
            av[0] = fmaf(p0[e], wvv, av[0]); av[1] = fmaf(p1[e], wvv, av[1]);
            av[2] = fmaf(p2[e], wvv, av[2]); av[3] = fmaf(p3[e], wvv, av[3]);
            ag[0] = fmaf(p0[e], wg, ag[0]); ag[1] = fmaf(p1[e], wg, ag[1]);
            ag[2] = fmaf(p2[e], wg, ag[2]); ag[3] = fmaf(p3[e], wg, ag[3]);
        }
    }
    const float kscale = 0.17677669529663687f;  // 1/sqrt(DH)
    float bgv = bg[col];
    #pragma unroll
    for (int r = 0; r < 4; r++) {
        const int orow = blockIdx.x*4 + r;
        qb[orow*DIN + col] = aq[r];
        vb[orow*DIN + col] = av[r];
        gb[orow*DIN + col] = 1.0f/(1.0f + __expf(-(ag[r] + bgv)));
    }
    *((float4*)&kT[col*LQ + blockIdx.x*4]) =
        make_float4(ak[0]*kscale, ak[1]*kscale, ak[2]*kscale, ak[3]*kscale);
}

// ---------------------------------------------------------------------------
// K2: bias streamer (R13 configuration — best known). Grid (2, 768), block
// 128 (2 waves). LDS 32KB -> 5 blocks/CU = 10 waves. Wave owns 192 keys =
// 3 key-blocks of 64; each = 8 d-stages of 64 keys x 16 dims (4KB tile,
// 4x gload_lds). 4-buffer rotation, steady vmcnt(12), tail 8/4/0.
// Lane = key: private LN stats + 8-head projection (no shuffles, no W2-LDS).
// ---------------------------------------------------------------------------
__global__ __launch_bounds__(128) void bias13_kernel(
    const float* __restrict__ bias, const float* __restrict__ W2g,
    const float* __restrict__ SCg, float* __restrict__ logits)
{
    __shared__ float tiles[2][4][1024];   // [wave][buf][4KB] = 32KB
    const int tid  = threadIdx.x;
    const int w    = tid >> 6;
    const int lane = tid & 63;            // = key within 64-key block
    const int q    = blockIdx.y;
    const int keybase = blockIdx.x * 384 + w * 192;

    const char* gq = (const char*)bias + ((size_t)q*LQ + keybase) * (DB*4);
    char* const lb0 = (char*)&tiles[w][0][0];

    // staging source offset (R12 involution): lane l' writes LDS
    // A = c*1024+l'*16; content dim-group rot = ((l'&3)-((l'>>3)&3))&3.
    const int keyc = lane >> 2;
    const int rot  = ((lane & 3) - ((lane >> 3) & 3)) & 3;
    const int soff = keyc*512 + rot*16;

    #define STAGE(T) {                                                       \
        const char* gt = gq + ((T) >> 3)*32768 + ((T) & 7)*64;               \
        char* lb = lb0 + (((T) & 3) << 12);                                  \
        _Pragma("unroll")                                                    \
        for (int c = 0; c < 4; c++)                                          \
            gload_lds16(gt + c*8192 + soff, lb + c*1024);                    \
    }

    // prologue: 4 tiles in flight
    STAGE(0); STAGE(1); STAGE(2); STAGE(3);

    float Sh[NH], Ch[NH];
    #pragma unroll
    for (int h = 0; h < NH; h++) { Sh[h] = SCg[h]; Ch[h] = SCg[NH + h]; }

    const int a0 = lane * 64;
    const int rl = (lane >> 1) & 3;

    float lo[3][NH];

    #pragma unroll
    for (int kb = 0; kb < 3; kb++) {
        float s = 0.f, ss = 0.f;
        float acc[NH] = {0,0,0,0,0,0,0,0};
        #pragma unroll 1
        for (int sd = 0; sd < 8; sd++) {
            const int T = kb*8 + sd;
            if (T <= 20)      asm volatile("s_waitcnt vmcnt(12)" ::: "memory");
            else if (T == 21) asm volatile("s_waitcnt vmcnt(8)"  ::: "memory");
            else if (T == 22) asm volatile("s_waitcnt vmcnt(4)"  ::: "memory");
            else              asm volatile("s_waitcnt vmcnt(0)"  ::: "memory");

            const char* tb = lb0 + ((T & 3) << 12);
            const float* wr0 = W2g + sd*16*NH;            // wave-uniform
            #pragma unroll
            for (int j = 0; j < 4; j++) {
                float4 bv = *(const float4*)(tb + a0 + (((rl + j) & 3) << 4));
                const float* wr = wr0 + j*4*NH;
                #pragma unroll
                for (int e = 0; e < 4; e++) {
                    float xv = (&bv.x)[e];
                    s += xv; ss = fmaf(xv, xv, ss);
                    #pragma unroll
                    for (int h = 0; h < NH; h++)
                        acc[h] = fmaf(xv, wr[e*NH + h], acc[h]);
                }
            }
            asm volatile("s_waitcnt lgkmcnt(0)" ::: "memory");  // WAR: reads done
            if (T + 4 < 24) STAGE(T + 4);
        }
        float mu  = s * (1.0f/DB);
        float inv = rsqrtf(ss * (1.0f/DB) - mu*mu + 1e-5f);
        #pragma unroll
        for (int h = 0; h < NH; h++)
            lo[kb][h] = fmaf(inv, fmaf(-mu, Sh[h], acc[h]), Ch[h]);
    }
    #undef STAGE

    // all DMA retired (vmcnt(0) above) -> store logits, coalesced
    #pragma unroll
    for (int kb = 0; kb < 3; kb++) {
        float4* dst = (float4*)(logits + ((size_t)q*LQ + keybase + kb*64 + lane)*NH);
        dst[0] = make_float4(lo[kb][0], lo[kb][1], lo[kb][2], lo[kb][3]);
        dst[1] = make_float4(lo[kb][4], lo[kb][5], lo[kb][6], lo[kb][7]);
    }
}

// ---------------------------------------------------------------------------
// K3: attn tail (R13 / R5-proven): logits -> pT transposed, add qk from kT,
// softmax (contiguous float4 rows), PV, gate, Wo. 2 q-rows/block, grid 384.
// ---------------------------------------------------------------------------
__global__ __launch_bounds__(256) void attn_kernel(
    const float* __restrict__ logits, const float* __restrict__ qbuf,
    const float* __restrict__ kT, const float* __restrict__ vbuf,
    const float* __restrict__ gb, const float* __restrict__ Wo,
    const float* __restrict__ bo, float* __restrict__ out)
{
    const int tid = threadIdx.x;
    const int q0 = blockIdx.x * 2;
    __shared__ float pT[2][NH][776];
    __shared__ float ao[2][DIN];
    __shared__ float isum[2][NH];

    #pragma unroll
    for (int r = 0; r < 2; r++) {
        const float4* rp = (const float4*)(logits + (size_t)(q0 + r)*LQ*NH);
        #pragma unroll
        for (int ii = 0; ii < 6; ii++) {
            int jj = ii*256 + tid;
            float4 t = rp[jj];
            int k = jj >> 1, h0 = (jj & 1) << 2;
            pT[r][h0+0][k] = t.x; pT[r][h0+1][k] = t.y;
            pT[r][h0+2][k] = t.z; pT[r][h0+3][k] = t.w;
        }
    }
    __syncthreads();

    if (tid < 192) {
        const float* q0p = qbuf + (size_t)q0*DIN;
        const float* q1p = q0p + DIN;
        #pragma unroll
        for (int h = 0; h < NH; h++) {
            float a00=0,a01=0,a02=0,a03=0, a10=0,a11=0,a12=0,a13=0;
            #pragma unroll
            for (int dd = 0; dd < DH; dd++) {
                const int d = h*DH + dd;
                float4 kv = *(const float4*)(kT + (size_t)d*LQ + tid*4);
                float qa = q0p[d], qc = q1p[d];
                a00 = fmaf(qa, kv.x, a00); a01 = fmaf(qa, kv.y, a01);
                a02 = fmaf(qa, kv.z, a02); a03 = fmaf(qa, kv.w, a03);
                a10 = fmaf(qc, kv.x, a10); a11 = fmaf(qc, kv.y, a11);
                a12 = fmaf(qc, kv.z, a12); a13 = fmaf(qc, kv.w, a13);
            }
            float4 p0 = *(float4*)&pT[0][h][tid*4];
            p0.x += a00; p0.y += a01; p0.z += a02; p0.w += a03;
            *(float4*)&pT[0][h][tid*4] = p0;
            float4 p1 = *(float4*)&pT[1][h][tid*4];
            p1.x += a10; p1.y += a11; p1.z += a12; p1.w += a13;
            *(float4*)&pT[1][h][tid*4] = p1;
        }
    }
    __syncthreads();

    {
        const int r = tid >> 7, h = (tid >> 4) & 7, l = tid & 15;
        float4* row = (float4*)&pT[r][h][0];
        float m = -1e30f;
        for (int i = l; i < 192; i += 16) {
            float4 v = row[i];
            m = fmaxf(m, fmaxf(fmaxf(v.x, v.y), fmaxf(v.z, v.w)));
        }
        #pragma unroll
        for (int mm = 1; mm <= 8; mm <<= 1) m = fmaxf(m, __shfl_xor(m, mm));
        float sum = 0.f;
        for (int i = l; i < 192; i += 16) {
            float4 v = row[i];
            v.x = __expf(v.x - m); v.y = __expf(v.y - m);
            v.z = __expf(v.z - m); v.w = __expf(v.w - m);
            sum += v.x + v.y + v.z + v.w;
            row[i] = v;
        }
        #pragma unroll
        for (int mm = 1; mm <= 8; mm <<= 1) sum += __shfl_xor(sum, mm);
        if (l == 0) isum[r][h] = 1.0f / sum;
    }
    __syncthreads();

    {
        const int h = tid >> 5, d = tid & 31;
        const float* vp = vbuf + h*DH + d;
        const float4* p0r = (const float4*)&pT[0][h][0];
        const float4* p1r = (const float4*)&pT[1][h][0];
        float a0 = 0.f, a1 = 0.f;
        for (int k4 = 0; k4 < 192; k4++) {
            float4 p0 = p0r[k4], p1 = p1r[k4];
            float v0 = vp[(size_t)(k4*4+0)*DIN];
            float v1 = vp[(size_t)(k4*4+1)*DIN];
            float v2 = vp[(size_t)(k4*4+2)*DIN];
            float v3 = vp[(size_t)(k4*4+3)*DIN];
            a0 = fmaf(p0.x, v0, a0); a0 = fmaf(p0.y, v1, a0);
            a0 = fmaf(p0.z, v2, a0); a0 = fmaf(p0.w, v3, a0);
            a1 = fmaf(p1.x, v0, a1); a1 = fmaf(p1.y, v1, a1);
            a1 = fmaf(p1.z, v2, a1); a1 = fmaf(p1.w, v3, a1);
        }
        ao[0][tid] = a0 * isum[0][h] * gb[(q0+0)*DIN + tid];
        ao[1][tid] = a1 * isum[1][h] * gb[(q0+1)*DIN + tid];
    }
    __syncthreads();

    {
        const int col = tid;
        float o0 = bo[col], o1 = o0;
        for (int i = 0; i < DIN; i++) {
            float wv = Wo[i*DIN + col];
            o0 = fmaf(ao[0][i], wv, o0);
            o1 = fmaf(ao[1][i], wv, o1);
        }
        out[(q0+0)*DIN + col] = o0;
        out[(q0+1)*DIN + col] = o1;
    }
}

extern "C" void kernel_launch(void* const* d_in, const int* in_sizes, int n_in,
                              void* d_out, int out_size, void* d_ws, size_t ws_size,
                              hipStream_t stream) {
    const float* x    = (const float*)d_in[0];
    const float* bias = (const float*)d_in[1];
    const float* lnw  = (const float*)d_in[2];
    const float* lnb  = (const float*)d_in[3];
    const float* lbw  = (const float*)d_in[4];
    const float* lbb  = (const float*)d_in[5];
    const float* Wq   = (const float*)d_in[6];
    const float* Wk   = (const float*)d_in[7];
    const float* Wv   = (const float*)d_in[8];
    const float* Wb   = (const float*)d_in[9];
    const float* Wg   = (const float*)d_in[10];
    const float* bg   = (const float*)d_in[11];
    const float* Wo   = (const float*)d_in[12];
    const float* bo   = (const float*)d_in[13];

    float* ws = (float*)d_ws;
    float* qb = ws + OFF_QB;
    float* kT = ws + OFF_KT;
    float* vb = ws + OFF_VB;
    float* gb = ws + OFF_GB;
    float* W2 = ws + OFF_W2;
    float* SC = ws + OFF_SC;
    float* lg = ws + OFF_LG;

    projsetup_kernel<<<193, 256, 0, stream>>>(x, lnw, lnb, Wq, Wk, Wv, Wg, bg,
                                              lbw, lbb, Wb, qb, kT, vb, gb, W2, SC);
    bias13_kernel<<<dim3(2, LQ), 128, 0, stream>>>(bias, W2, SC, lg);
    attn_kernel<<<LQ/2, 256, 0, stream>>>(lg, qb, kT, vb, gb, Wo, bo, (float*)d_out);
}